// Round 14
// baseline (105.450 us; speedup 1.0000x reference)
//
#include <hip/hip_runtime.h>

#define SD 2048
#define HD 1024
#define BD 4

typedef __bf16 bf16_t;
typedef bf16_t bf16x8 __attribute__((ext_vector_type(8)));
typedef float f32x4 __attribute__((ext_vector_type(4)));
typedef unsigned short ushortx8 __attribute__((ext_vector_type(8)));
typedef unsigned short ushort_t;

__device__ inline unsigned short f2bf(float f) {
  return __builtin_bit_cast(unsigned short, (__bf16)f);
}

__device__ inline float bf2f(unsigned short u) {
  return __builtin_bit_cast(float, (unsigned)u << 16);
}

__device__ inline void gload_lds16(const void* g, void* l) {
  __builtin_amdgcn_global_load_lds(
      (const __attribute__((address_space(1))) void*)g,
      (__attribute__((address_space(3))) void*)l, 16, 0, 0);
}

// Stage ROWS x 64 bf16 tile into LDS. Dest is LINEAR in chunk id (m104/m108:
// global_load_lds writes base+lane*16); T2 XOR swizzle applied on the GLOBAL
// source chunk and again on the ds_read side (rule #21).
template <int ROWS>
__device__ inline void stage_rows(const ushort_t* __restrict__ src, int r0, int k0,
                                  int tid, ushort_t* lds)
{
#pragma unroll
  for (int it = 0; it < ROWS / 32; ++it) {
    int c   = it * 256 + tid;        // chunk id; LDS byte offset = c*16
    int row = c >> 3;
    int kc8 = c & 7;
    int kcs = kc8 ^ (row & 7);
    gload_lds16(&src[(size_t)(r0 + row) * HD + k0 + kcs * 8], &lds[c * 8]);
  }
}

// Swizzled LDS read of an 8-elem bf16 fragment: row-major [ROWS][64] + XOR.
__device__ inline bf16x8 lds_frag(const ushort_t* l, int row, int kc8) {
  int kcs = kc8 ^ (row & 7);
  return *(const bf16x8*)&l[row * 64 + kcs * 8];
}

// ---------------------------------------------------------------------------
// 1) prep: cvt only — Xb = bf16(relu(X[0])), Wkb, Wqb. Grid 2048, one-shot.
// ---------------------------------------------------------------------------
__global__ __launch_bounds__(256) void prep(
    const float* __restrict__ X, const float* __restrict__ Wk,
    const float* __restrict__ Wq, ushort_t* __restrict__ Xb,
    ushort_t* __restrict__ Wkb, ushort_t* __restrict__ Wqb)
{
  const int n8x = SD * HD / 8;
  const int n8w = HD * HD / 8;
  const int e = blockIdx.x * 256 + threadIdx.x;   // total 524288 = 2048*256
  const float4* s4; ushortx8* d8; int idx; bool relu;
  if (e < n8x)            { s4 = (const float4*)X;  d8 = (ushortx8*)Xb;  idx = e;             relu = true; }
  else if (e < n8x + n8w) { s4 = (const float4*)Wk; d8 = (ushortx8*)Wkb; idx = e - n8x;       relu = false; }
  else                    { s4 = (const float4*)Wq; d8 = (ushortx8*)Wqb; idx = e - n8x - n8w; relu = false; }
  float4 a = s4[idx * 2], b4 = s4[idx * 2 + 1];
  float v[8] = {a.x, a.y, a.z, a.w, b4.x, b4.y, b4.z, b4.w};
  ushortx8 o;
#pragma unroll
  for (int j = 0; j < 8; ++j) {
    float f = v[j];
    if (relu) f = fmaxf(f, 0.0f);
    o[j] = f2bf(f);
  }
  d8[idx] = o;
}

// ---------------------------------------------------------------------------
// 2) gemm_kq dispatch, 736 blocks, three roles:
//    bid 0..255   -> K/Q GEMM (128x128 tile, XCD swizzle, 1/CU — slot 1)
//    bid 256..351 -> xsum partials of relu(X[1:4]) (100 MB read — slot 2)
//    bid 352..735 -> p_attn[1:4] = 1/S fill (50 MB write — slot 2)
// ---------------------------------------------------------------------------
__global__ __launch_bounds__(256, 2) void gemm_kq(
    const ushort_t* __restrict__ Xb, const ushort_t* __restrict__ Wkb,
    const ushort_t* __restrict__ Wqb, const float* __restrict__ bk,
    const float* __restrict__ bq, ushort_t* __restrict__ Kb,
    ushort_t* __restrict__ Qb, const float* __restrict__ X,
    float* __restrict__ part, float* __restrict__ patRest)
{
  __shared__ __align__(16) ushort_t lA[2][8192];   // 128x64
  __shared__ __align__(16) ushort_t lB[2][8192];   // 128x64

  const int bid = blockIdx.x;
  const int tid = threadIdx.x;

  if (bid >= 352) {
    // fill role: p_attn[1:4] = 1/S (384 blocks)
    const int f = bid - 352;
    const int nf4 = 3 * SD * (SD / 4);
    const float uf = 1.0f / SD;
    float4 v = make_float4(uf, uf, uf, uf);
    float4* p4 = (float4*)patRest;
    for (int e = f * 256 + tid; e < nf4; e += 384 * 256) p4[e] = v;
    return;
  }
  if (bid >= 256) {
    // xsum role: column partials of relu(X[1:4]) (96 blocks, 64 rows each)
    const int cid = bid - 256;
    const int b = cid >> 5;
    const int sub = cid & 31;
    const float4* Xp = (const float4*)(X + (size_t)(b + 1) * SD * HD + (size_t)sub * 64 * HD);
    float4 acc = make_float4(0.f, 0.f, 0.f, 0.f);
#pragma unroll 4
    for (int rr = 0; rr < 64; ++rr) {
      float4 v = Xp[rr * 256 + tid];
      acc.x += fmaxf(v.x, 0.f); acc.y += fmaxf(v.y, 0.f);
      acc.z += fmaxf(v.z, 0.f); acc.w += fmaxf(v.w, 0.f);
    }
    ((float4*)part)[((size_t)b * 32 + sub) * 256 + tid] = acc;
    return;
  }

  // GEMM role. XCD-chunked swizzle: 256 = 8 XCDs x 32 chunk (bijective)
  const int wg = ((bid & 7) << 5) | (bid >> 3);
  const int bm = wg >> 4, bn = wg & 15;
  const int half = bn >> 3;
  const ushort_t* Bm = half ? Wqb : Wkb;
  const int m0 = bm * 128, n0 = (bn & 7) * 128;

  const int lane = tid & 63;
  const int wave = tid >> 6;
  const int wm = wave >> 1, wn = wave & 1;   // per-wave 64x64 output

  f32x4 acc[4][4] = {};

  stage_rows<128>(Xb, m0, 0, tid, lA[0]);
  stage_rows<128>(Bm, n0, 0, tid, lB[0]);
  __syncthreads();

  for (int t = 0; t < 16; ++t) {
    const int cur = t & 1;
    if (t < 15) {
      stage_rows<128>(Xb, m0, (t + 1) * 64, tid, lA[cur ^ 1]);
      stage_rows<128>(Bm, n0, (t + 1) * 64, tid, lB[cur ^ 1]);
    }
#pragma unroll
    for (int h = 0; h < 2; ++h) {
      bf16x8 af[4], bfr[4];
#pragma unroll
      for (int mi = 0; mi < 4; ++mi)
        af[mi] = lds_frag(lA[cur], wm * 64 + mi * 16 + (lane & 15), h * 4 + (lane >> 4));
#pragma unroll
      for (int ni = 0; ni < 4; ++ni)
        bfr[ni] = lds_frag(lB[cur], wn * 64 + ni * 16 + (lane & 15), h * 4 + (lane >> 4));
#pragma unroll
      for (int mi = 0; mi < 4; ++mi)
#pragma unroll
        for (int ni = 0; ni < 4; ++ni)
          acc[mi][ni] = __builtin_amdgcn_mfma_f32_16x16x32_bf16(af[mi], bfr[ni], acc[mi][ni], 0, 0, 0);
    }
    __syncthreads();
  }

  const int rb = (lane >> 4) * 4;
  const int cc = lane & 15;
  const float* bias = half ? bq : bk;
  ushort_t* dst = half ? Qb : Kb;
#pragma unroll
  for (int ni = 0; ni < 4; ++ni) {
    int col = n0 + wn * 64 + ni * 16 + cc;
    float bv = bias[col];
#pragma unroll
    for (int mi = 0; mi < 4; ++mi) {
#pragma unroll
      for (int j = 0; j < 4; ++j) {
        int row = m0 + wm * 64 + mi * 16 + rb + j;
        dst[(size_t)row * HD + col] = f2bf(acc[mi][ni][j] + bv);
      }
    }
  }
}

// ---------------------------------------------------------------------------
// 3) band_cm: blocks 0..125 -> banded scores (64x64 tiles x split-K(2)),
//             blocks 126..173 -> colmean matvec (reads part from gemm_kq)
// ---------------------------------------------------------------------------
__global__ __launch_bounds__(256, 2) void band_cm(
    const ushort_t* __restrict__ Q, const ushort_t* __restrict__ K,
    float* __restrict__ Sb0, float* __restrict__ Sb1,
    const float* __restrict__ part, const float* __restrict__ Wk,
    const float* __restrict__ bk, float* __restrict__ cm)
{
  __shared__ __align__(16) char smem[32768];
  const int bid = blockIdx.x;
  const int tid = threadIdx.x;

  if (bid < 126) {
    const int tt = bid >> 1;
    const int ks = bid & 1;
    const int blk = (tt + 1) >> 1;
    const int tcol = (tt + 1) & 1;
    const int m0 = blk * 64;
    const int n0 = (blk - 1 + tcol) * 64;
    float* Sb = ks ? Sb1 : Sb0;

    const int lane = tid & 63;
    const int wave = tid >> 6;
    const int wm = wave >> 1, wn = wave & 1;   // per-wave 32x32 output

    ushort_t* lA = (ushort_t*)smem;            // [2][4096]
    ushort_t* lB = (ushort_t*)(smem + 16384);  // [2][4096]

    f32x4 acc[2][2] = {};

    const int kbase = ks * 512;
    stage_rows<64>(Q, m0, kbase, tid, lA);
    stage_rows<64>(K, n0, kbase, tid, lB);
    __syncthreads();

    for (int t = 0; t < 8; ++t) {
      const int cur = t & 1;
      if (t < 7) {
        stage_rows<64>(Q, m0, kbase + (t + 1) * 64, tid, lA + (cur ^ 1) * 4096);
        stage_rows<64>(K, n0, kbase + (t + 1) * 64, tid, lB + (cur ^ 1) * 4096);
      }
#pragma unroll
      for (int h = 0; h < 2; ++h) {
        bf16x8 af[2], bfr[2];
#pragma unroll
        for (int mi = 0; mi < 2; ++mi)
          af[mi] = lds_frag(lA + cur * 4096, wm * 32 + mi * 16 + (lane & 15), h * 4 + (lane >> 4));
#pragma unroll
        for (int ni = 0; ni < 2; ++ni)
          bfr[ni] = lds_frag(lB + cur * 4096, wn * 32 + ni * 16 + (lane & 15), h * 4 + (lane >> 4));
#pragma unroll
        for (int mi = 0; mi < 2; ++mi)
#pragma unroll
          for (int ni = 0; ni < 2; ++ni)
            acc[mi][ni] = __builtin_amdgcn_mfma_f32_16x16x32_bf16(af[mi], bfr[ni], acc[mi][ni], 0, 0, 0);
      }
      __syncthreads();
    }

    const int rb = (lane >> 4) * 4;
    const int cc = lane & 15;
#pragma unroll
    for (int ni = 0; ni < 2; ++ni) {
      int ccol = tcol * 64 + wn * 32 + ni * 16 + cc;
#pragma unroll
      for (int mi = 0; mi < 2; ++mi)
#pragma unroll
        for (int j = 0; j < 4; ++j) {
          int row = m0 + wm * 32 + mi * 16 + rb + j;
          Sb[(size_t)row * 128 + ccol] = acc[mi][ni][j] * 0.03125f;
        }
    }
    return;
  }

  // colmean role: cid in [0,48): b = cid>>4, og = cid&15
  {
    const int cid = bid - 126;
    const int b = cid >> 4, og = cid & 15;
    float* xs = (float*)smem;                  // 1024 floats
#pragma unroll
    for (int k = 0; k < 4; ++k) {
      int h = tid + 256 * k;
      float a = 0;
#pragma unroll 8
      for (int rc = 0; rc < 32; ++rc) a += part[((size_t)b * 32 + rc) * HD + h];
      xs[h] = a;
    }
    __syncthreads();
    const int o = og * 64 + (tid >> 2);
    const int q = tid & 3;
    const f32x4* wr = (const f32x4*)(Wk + (size_t)o * HD);
    const f32x4* x4 = (const f32x4*)xs;
    float a = 0;
#pragma unroll 8
    for (int i = 0; i < 64; ++i) {
      f32x4 w = wr[q * 64 + i], x = x4[q * 64 + i];
      a += w[0] * x[0] + w[1] * x[1] + w[2] * x[2] + w[3] * x[3];
    }
    a += __shfl_xor(a, 1);
    a += __shfl_xor(a, 2);
    if (q == 0) cm[b * HD + o] = a * (1.0f / SD) + bk[o];
  }
}

// ---------------------------------------------------------------------------
// 4) pv_epi: blocks 0..511    -> softmax+PV (32 q-rows x 128 H-cols each;
//                                K staged from bf16 with shift-convert)
//            blocks 512..1023 -> p_attn[0] rows (zeros + band probs)
//            blocks 1024..1535-> out[1:4] broadcast of cm
// ---------------------------------------------------------------------------
__global__ __launch_bounds__(256, 2) void pv_epi(
    const float* __restrict__ Sb0, const float* __restrict__ Sb1,
    const ushort_t* __restrict__ Kb, const float* __restrict__ cm,
    float* __restrict__ out0, float* __restrict__ P0,
    float* __restrict__ out123)
{
  __shared__ __align__(16) float smem[15488];   // 61952 B
  const int bid = blockIdx.x;
  const int t = threadIdx.x;

  if (bid < 512) {
    float* Ks  = smem;            // [96][128]
    float* spl = smem + 12288;    // [32][100] padded
    const int i0 = (bid >> 3) * 32;
    const int hc = bid & 7;       // 128 cols each

    // stage K rows [i0-64, i0+31] from bf16, converting to f32
    for (int e = t; e < 96 * 16; e += 256) {
      int lr = e >> 4, c8 = e & 15;
      int gr = i0 - 64 + lr;
      if (gr < 0) gr = 0;
      ushortx8 u = *(const ushortx8*)&Kb[(size_t)gr * HD + hc * 128 + c8 * 8];
      f32x4 f0 = {bf2f(u[0]), bf2f(u[1]), bf2f(u[2]), bf2f(u[3])};
      f32x4 f1 = {bf2f(u[4]), bf2f(u[5]), bf2f(u[6]), bf2f(u[7])};
      *(f32x4*)&Ks[lr * 128 + c8 * 8]     = f0;
      *(f32x4*)&Ks[lr * 128 + c8 * 8 + 4] = f1;
    }

    {
      const int r = t >> 3, sub = t & 7;
      const int i = i0 + r;
      const int jlo = (i >= 64) ? i - 64 : 0;
      const int scoff = i0 & 32;  // Sb col = lj + scoff
      float sv[12];
      float m = -1e30f;
#pragma unroll
      for (int k = 0; k < 12; ++k) {
        int lj = sub + 8 * k;
        int gj = i0 - 64 + lj;
        bool val = (gj >= jlo) && (gj <= i);
        float s = -1e30f;
        if (val) {
          size_t sidx = (size_t)i * 128 + lj + scoff;
          s = Sb0[sidx] + Sb1[sidx];
        }
        sv[k] = s;
        m = fmaxf(m, s);
      }
#pragma unroll
      for (int off = 1; off < 8; off <<= 1) m = fmaxf(m, __shfl_xor(m, off));
      float p[12], sum = 0;
#pragma unroll
      for (int k = 0; k < 12; ++k) {
        p[k] = (sv[k] > -1e29f) ? __expf(sv[k] - m) : 0.0f;
        sum += p[k];
      }
#pragma unroll
      for (int off = 1; off < 8; off <<= 1) sum += __shfl_xor(sum, off);
      float inv = 1.0f / sum;
#pragma unroll
      for (int k = 0; k < 12; ++k) spl[r * 100 + sub + 8 * k] = p[k] * inv;
    }
    __syncthreads();

    const int r = t >> 3;               // 0..31
    const int g = t & 7;                // col sub-group
    f32x4 a0 = {0,0,0,0}, a1 = {0,0,0,0}, a2 = {0,0,0,0}, a3 = {0,0,0,0};
    for (int lj = 0; lj < 96; ++lj) {
      float pv = spl[r * 100 + lj];
      const float* kr = &Ks[lj * 128 + g * 4];
      a0 += pv * *(const f32x4*)(kr);
      a1 += pv * *(const f32x4*)(kr + 32);
      a2 += pv * *(const f32x4*)(kr + 64);
      a3 += pv * *(const f32x4*)(kr + 96);
    }
    float* ob = out0 + (size_t)(i0 + r) * HD + hc * 128 + g * 4;
    *(f32x4*)(ob)      = a0;
    *(f32x4*)(ob + 32) = a1;
    *(f32x4*)(ob + 64) = a2;
    *(f32x4*)(ob + 96) = a3;
    return;
  }

  if (bid < 1024) {
    // p_attn[0] band rows: 4 rows/block, one wave per row
    float* probs = smem;                 // [4][68]
    const int widx = t >> 6;
    const int lane = t & 63;
    const int i = (bid - 512) * 4 + widx;
    const int jlo = (i >= 64) ? i - 64 : 0;
    const int cnt = i - jlo + 1;         // <= 65
    const int base = ((i >> 6) - 1) * 64;

    float s0 = -1e30f;
    if (lane < cnt) {
      size_t c = (size_t)i * 128 + (jlo - base + lane);
      s0 = Sb0[c] + Sb1[c];
    }
    float s1 = -1e30f;
    if (cnt == 65) {
      size_t c = (size_t)i * 128 + (jlo - base + 64);
      s1 = Sb0[c] + Sb1[c];
    }
    float m = s0;
#pragma unroll
    for (int off = 1; off < 64; off <<= 1) m = fmaxf(m, __shfl_xor(m, off));
    m = fmaxf(m, s1);
    float p0 = (lane < cnt) ? __expf(s0 - m) : 0.0f;
    float p1 = (cnt == 65) ? __expf(s1 - m) : 0.0f;  // lane-uniform
    float sum = p0;
#pragma unroll
    for (int off = 1; off < 64; off <<= 1) sum += __shfl_xor(sum, off);
    sum += p1;
    float inv = 1.0f / sum;
    if (lane < cnt) probs[widx * 68 + lane] = p0 * inv;
    if (lane == 0 && cnt == 65) probs[widx * 68 + 64] = p1 * inv;
    __syncthreads();

    float4* rowp = (float4*)(P0 + (size_t)i * SD);
#pragma unroll
    for (int k = 0; k < 8; ++k) {
      int f4i = k * 64 + lane;
      int j0 = f4i * 4;
      float4 v = make_float4(0.f, 0.f, 0.f, 0.f);
      if (j0 + 3 >= jlo && j0 <= i) {
        float* vv = (float*)&v;
#pragma unroll
        for (int q = 0; q < 4; ++q) {
          int j = j0 + q;
          if (j >= jlo && j <= i) vv[q] = probs[widx * 68 + (j - jlo)];
        }
      }
      rowp[f4i] = v;
    }
    return;
  }

  // out[1:4] broadcast
  {
    const int nf4 = 3 * SD * (HD / 4);
    const int per_b = SD * (HD / 4);
    const f32x4* cm4 = (const f32x4*)cm;
    f32x4* o4 = (f32x4*)out123;
    for (int idx = (bid - 1024) * 256 + t; idx < nf4; idx += 512 * 256) {
      int b = idx / per_b;
      int h4 = idx & (HD / 4 - 1);
      o4[idx] = cm4[b * (HD / 4) + h4];
    }
  }
}

extern "C" void kernel_launch(void* const* d_in, const int* in_sizes, int n_in,
                              void* d_out, int out_size, void* d_ws, size_t ws_size,
                              hipStream_t stream)
{
  (void)in_sizes; (void)n_in; (void)out_size; (void)ws_size;
  const float* X  = (const float*)d_in[0];
  const float* Wk = (const float*)d_in[1];
  const float* bk = (const float*)d_in[2];
  const float* Wq = (const float*)d_in[3];
  const float* bq = (const float*)d_in[4];
  // d_in[5] = k_mul = 64 (band width, hard-coded)

  float* out = (float*)d_out;                   // (B,S,H)
  float* pat = out + (size_t)BD * SD * HD;      // (B,S,S)

  char* w = (char*)d_ws;
  ushort_t* Xb   = (ushort_t*)w; w += (size_t)SD * HD * 2;       // relu(X[0]) bf16
  ushort_t* Wkb  = (ushort_t*)w; w += (size_t)HD * HD * 2;
  ushort_t* Wqb  = (ushort_t*)w; w += (size_t)HD * HD * 2;
  ushort_t* Kb0  = (ushort_t*)w; w += (size_t)SD * HD * 2;       // K[0] bf16
  ushort_t* Q0b  = (ushort_t*)w; w += (size_t)SD * HD * 2;       // Q[0] bf16
  float*    part = (float*)w;    w += (size_t)3 * 32 * HD * 4;   // xsum partials
  float*    cm   = (float*)w;    w += (size_t)3 * HD * 4;        // colmeans b=1..3
  float*    Sb0  = (float*)w;    w += (size_t)SD * 128 * 4;      // band scores, K-half 0
  float*    Sb1  = (float*)w;    w += (size_t)SD * 128 * 4;      // band scores, K-half 1

  // MEASUREMENT ROUND: duplicate prep/band_cm/pv_epi (idempotent) so
  // G(gemm dispatch) = 2*69.9 - dur. Revert to single launches next round.
  prep<<<2048, 256, 0, stream>>>(X, Wk, Wq, Xb, Wkb, Wqb);
  prep<<<2048, 256, 0, stream>>>(X, Wk, Wq, Xb, Wkb, Wqb);
  gemm_kq<<<736, 256, 0, stream>>>(Xb, Wkb, Wqb, bk, bq, Kb0, Q0b, X, part,
                                   pat + (size_t)SD * SD);
  band_cm<<<174, 256, 0, stream>>>(Q0b, Kb0, Sb0, Sb1, part, Wk, bk, cm);
  band_cm<<<174, 256, 0, stream>>>(Q0b, Kb0, Sb0, Sb1, part, Wk, bk, cm);
  pv_epi<<<1536, 256, 0, stream>>>(Sb0, Sb1, Kb0, cm, out, pat, out + (size_t)SD * HD);
  pv_epi<<<1536, 256, 0, stream>>>(Sb0, Sb1, Kb0, cm, out, pat, out + (size_t)SD * HD);
}

// Round 15
// 68.613 us; speedup vs baseline: 1.5369x; 1.5369x over previous
//
#include <hip/hip_runtime.h>

#define SD 2048
#define HD 1024
#define BD 4

typedef __bf16 bf16_t;
typedef bf16_t bf16x8 __attribute__((ext_vector_type(8)));
typedef float f32x4 __attribute__((ext_vector_type(4)));
typedef unsigned short ushortx8 __attribute__((ext_vector_type(8)));
typedef unsigned short ushort_t;

__device__ inline unsigned short f2bf(float f) {
  return __builtin_bit_cast(unsigned short, (__bf16)f);
}

__device__ inline float bf2f(unsigned short u) {
  return __builtin_bit_cast(float, (unsigned)u << 16);
}

__device__ inline void gload_lds16(const void* g, void* l) {
  __builtin_amdgcn_global_load_lds(
      (const __attribute__((address_space(1))) void*)g,
      (__attribute__((address_space(3))) void*)l, 16, 0, 0);
}

// Stage ROWS x 64 bf16 tile into LDS. Dest is LINEAR in chunk id (m104/m108:
// global_load_lds writes base+lane*16); T2 XOR swizzle applied on the GLOBAL
// source chunk and again on the ds_read side (rule #21).
template <int ROWS>
__device__ inline void stage_rows(const ushort_t* __restrict__ src, int r0, int k0,
                                  int tid, ushort_t* lds)
{
#pragma unroll
  for (int it = 0; it < ROWS / 32; ++it) {
    int c   = it * 256 + tid;        // chunk id; LDS byte offset = c*16
    int row = c >> 3;
    int kc8 = c & 7;
    int kcs = kc8 ^ (row & 7);
    gload_lds16(&src[(size_t)(r0 + row) * HD + k0 + kcs * 8], &lds[c * 8]);
  }
}

// Swizzled LDS read of an 8-elem bf16 fragment: row-major [ROWS][64] + XOR.
__device__ inline bf16x8 lds_frag(const ushort_t* l, int row, int kc8) {
  int kcs = kc8 ^ (row & 7);
  return *(const bf16x8*)&l[row * 64 + kcs * 8];
}

// ---------------------------------------------------------------------------
// 1) prep: cvt only — Xb = bf16(relu(X[0])), Wkb, Wqb. Grid 2048, one-shot.
// ---------------------------------------------------------------------------
__global__ __launch_bounds__(256) void prep(
    const float* __restrict__ X, const float* __restrict__ Wk,
    const float* __restrict__ Wq, ushort_t* __restrict__ Xb,
    ushort_t* __restrict__ Wkb, ushort_t* __restrict__ Wqb)
{
  const int n8x = SD * HD / 8;
  const int n8w = HD * HD / 8;
  const int e = blockIdx.x * 256 + threadIdx.x;   // total 524288 = 2048*256
  const float4* s4; ushortx8* d8; int idx; bool relu;
  if (e < n8x)            { s4 = (const float4*)X;  d8 = (ushortx8*)Xb;  idx = e;             relu = true; }
  else if (e < n8x + n8w) { s4 = (const float4*)Wk; d8 = (ushortx8*)Wkb; idx = e - n8x;       relu = false; }
  else                    { s4 = (const float4*)Wq; d8 = (ushortx8*)Wqb; idx = e - n8x - n8w; relu = false; }
  float4 a = s4[idx * 2], b4 = s4[idx * 2 + 1];
  float v[8] = {a.x, a.y, a.z, a.w, b4.x, b4.y, b4.z, b4.w};
  ushortx8 o;
#pragma unroll
  for (int j = 0; j < 8; ++j) {
    float f = v[j];
    if (relu) f = fmaxf(f, 0.0f);
    o[j] = f2bf(f);
  }
  d8[idx] = o;
}

// ---------------------------------------------------------------------------
// 2) gemm_kq dispatch, 480 blocks, three roles:
//    bid 0..255   -> K/Q GEMM (128x128 tile, XCD swizzle, 1/CU — slot 1)
//    bid 256..351 -> xsum partials of relu(X[1:4]) (100 MB read — slot 2)
//    bid 352..479 -> p_attn[0] = 0 zero-fill (16 MB; pv scatters probs later)
//    Helpers total ~116 MB ≈ 21 us < GEMM ~27 us -> dispatch is GEMM-bound.
// ---------------------------------------------------------------------------
__global__ __launch_bounds__(256, 2) void gemm_kq(
    const ushort_t* __restrict__ Xb, const ushort_t* __restrict__ Wkb,
    const ushort_t* __restrict__ Wqb, const float* __restrict__ bk,
    const float* __restrict__ bq, ushort_t* __restrict__ Kb,
    ushort_t* __restrict__ Qb, const float* __restrict__ X,
    float* __restrict__ part, float* __restrict__ P0)
{
  __shared__ __align__(16) ushort_t lA[2][8192];   // 128x64
  __shared__ __align__(16) ushort_t lB[2][8192];   // 128x64

  const int bid = blockIdx.x;
  const int tid = threadIdx.x;

  if (bid >= 352) {
    // zero-fill role: p_attn[0] = 0 (128 blocks, SD*SD/4 float4s)
    const int f = bid - 352;
    const int nf4 = SD * (SD / 4);
    float4 z = make_float4(0.f, 0.f, 0.f, 0.f);
    float4* p4 = (float4*)P0;
    for (int e = f * 256 + tid; e < nf4; e += 128 * 256) p4[e] = z;
    return;
  }
  if (bid >= 256) {
    // xsum role: column partials of relu(X[1:4]) (96 blocks, 64 rows each)
    const int cid = bid - 256;
    const int b = cid >> 5;
    const int sub = cid & 31;
    const float4* Xp = (const float4*)(X + (size_t)(b + 1) * SD * HD + (size_t)sub * 64 * HD);
    float4 acc = make_float4(0.f, 0.f, 0.f, 0.f);
#pragma unroll 4
    for (int rr = 0; rr < 64; ++rr) {
      float4 v = Xp[rr * 256 + tid];
      acc.x += fmaxf(v.x, 0.f); acc.y += fmaxf(v.y, 0.f);
      acc.z += fmaxf(v.z, 0.f); acc.w += fmaxf(v.w, 0.f);
    }
    ((float4*)part)[((size_t)b * 32 + sub) * 256 + tid] = acc;
    return;
  }

  // GEMM role. XCD-chunked swizzle: 256 = 8 XCDs x 32 chunk (bijective)
  const int wg = ((bid & 7) << 5) | (bid >> 3);
  const int bm = wg >> 4, bn = wg & 15;
  const int half = bn >> 3;
  const ushort_t* Bm = half ? Wqb : Wkb;
  const int m0 = bm * 128, n0 = (bn & 7) * 128;

  const int lane = tid & 63;
  const int wave = tid >> 6;
  const int wm = wave >> 1, wn = wave & 1;   // per-wave 64x64 output

  f32x4 acc[4][4] = {};

  stage_rows<128>(Xb, m0, 0, tid, lA[0]);
  stage_rows<128>(Bm, n0, 0, tid, lB[0]);
  __syncthreads();

  for (int t = 0; t < 16; ++t) {
    const int cur = t & 1;
    if (t < 15) {
      stage_rows<128>(Xb, m0, (t + 1) * 64, tid, lA[cur ^ 1]);
      stage_rows<128>(Bm, n0, (t + 1) * 64, tid, lB[cur ^ 1]);
    }
#pragma unroll
    for (int h = 0; h < 2; ++h) {
      bf16x8 af[4], bfr[4];
#pragma unroll
      for (int mi = 0; mi < 4; ++mi)
        af[mi] = lds_frag(lA[cur], wm * 64 + mi * 16 + (lane & 15), h * 4 + (lane >> 4));
#pragma unroll
      for (int ni = 0; ni < 4; ++ni)
        bfr[ni] = lds_frag(lB[cur], wn * 64 + ni * 16 + (lane & 15), h * 4 + (lane >> 4));
#pragma unroll
      for (int mi = 0; mi < 4; ++mi)
#pragma unroll
        for (int ni = 0; ni < 4; ++ni)
          acc[mi][ni] = __builtin_amdgcn_mfma_f32_16x16x32_bf16(af[mi], bfr[ni], acc[mi][ni], 0, 0, 0);
    }
    __syncthreads();
  }

  const int rb = (lane >> 4) * 4;
  const int cc = lane & 15;
  const float* bias = half ? bq : bk;
  ushort_t* dst = half ? Qb : Kb;
#pragma unroll
  for (int ni = 0; ni < 4; ++ni) {
    int col = n0 + wn * 64 + ni * 16 + cc;
    float bv = bias[col];
#pragma unroll
    for (int mi = 0; mi < 4; ++mi) {
#pragma unroll
      for (int j = 0; j < 4; ++j) {
        int row = m0 + wm * 64 + mi * 16 + rb + j;
        dst[(size_t)row * HD + col] = f2bf(acc[mi][ni][j] + bv);
      }
    }
  }
}

// ---------------------------------------------------------------------------
// 3) band_cm: blocks 0..125  -> banded scores (64x64 tiles x split-K(2))
//             blocks 126..173 -> colmean matvec (reads part from gemm_kq)
//             blocks 174..557 -> p_attn[1:4] = 1/S fill (50 MB — band/colmean
//                                are latency-bound with idle BW; fill soaks it)
// ---------------------------------------------------------------------------
__global__ __launch_bounds__(256, 2) void band_cm(
    const ushort_t* __restrict__ Q, const ushort_t* __restrict__ K,
    float* __restrict__ Sb0, float* __restrict__ Sb1,
    const float* __restrict__ part, const float* __restrict__ Wk,
    const float* __restrict__ bk, float* __restrict__ cm,
    float* __restrict__ patRest)
{
  __shared__ __align__(16) char smem[32768];
  const int bid = blockIdx.x;
  const int tid = threadIdx.x;

  if (bid >= 174) {
    // fill role: p_attn[1:4] = 1/S (384 blocks)
    const int f = bid - 174;
    const int nf4 = 3 * SD * (SD / 4);
    const float uf = 1.0f / SD;
    float4 v = make_float4(uf, uf, uf, uf);
    float4* p4 = (float4*)patRest;
    for (int e = f * 256 + tid; e < nf4; e += 384 * 256) p4[e] = v;
    return;
  }

  if (bid < 126) {
    const int tt = bid >> 1;
    const int ks = bid & 1;
    const int blk = (tt + 1) >> 1;
    const int tcol = (tt + 1) & 1;
    const int m0 = blk * 64;
    const int n0 = (blk - 1 + tcol) * 64;
    float* Sb = ks ? Sb1 : Sb0;

    const int lane = tid & 63;
    const int wave = tid >> 6;
    const int wm = wave >> 1, wn = wave & 1;   // per-wave 32x32 output

    ushort_t* lA = (ushort_t*)smem;            // [2][4096]
    ushort_t* lB = (ushort_t*)(smem + 16384);  // [2][4096]

    f32x4 acc[2][2] = {};

    const int kbase = ks * 512;
    stage_rows<64>(Q, m0, kbase, tid, lA);
    stage_rows<64>(K, n0, kbase, tid, lB);
    __syncthreads();

    for (int t = 0; t < 8; ++t) {
      const int cur = t & 1;
      if (t < 7) {
        stage_rows<64>(Q, m0, kbase + (t + 1) * 64, tid, lA + (cur ^ 1) * 4096);
        stage_rows<64>(K, n0, kbase + (t + 1) * 64, tid, lB + (cur ^ 1) * 4096);
      }
#pragma unroll
      for (int h = 0; h < 2; ++h) {
        bf16x8 af[2], bfr[2];
#pragma unroll
        for (int mi = 0; mi < 2; ++mi)
          af[mi] = lds_frag(lA + cur * 4096, wm * 32 + mi * 16 + (lane & 15), h * 4 + (lane >> 4));
#pragma unroll
        for (int ni = 0; ni < 2; ++ni)
          bfr[ni] = lds_frag(lB + cur * 4096, wn * 32 + ni * 16 + (lane & 15), h * 4 + (lane >> 4));
#pragma unroll
        for (int mi = 0; mi < 2; ++mi)
#pragma unroll
          for (int ni = 0; ni < 2; ++ni)
            acc[mi][ni] = __builtin_amdgcn_mfma_f32_16x16x32_bf16(af[mi], bfr[ni], acc[mi][ni], 0, 0, 0);
      }
      __syncthreads();
    }

    const int rb = (lane >> 4) * 4;
    const int cc = lane & 15;
#pragma unroll
    for (int ni = 0; ni < 2; ++ni) {
      int ccol = tcol * 64 + wn * 32 + ni * 16 + cc;
#pragma unroll
      for (int mi = 0; mi < 2; ++mi)
#pragma unroll
        for (int j = 0; j < 4; ++j) {
          int row = m0 + wm * 32 + mi * 16 + rb + j;
          Sb[(size_t)row * 128 + ccol] = acc[mi][ni][j] * 0.03125f;
        }
    }
    return;
  }

  // colmean role: cid in [0,48): b = cid>>4, og = cid&15
  {
    const int cid = bid - 126;
    const int b = cid >> 4, og = cid & 15;
    float* xs = (float*)smem;                  // 1024 floats
#pragma unroll
    for (int k = 0; k < 4; ++k) {
      int h = tid + 256 * k;
      float a = 0;
#pragma unroll 8
      for (int rc = 0; rc < 32; ++rc) a += part[((size_t)b * 32 + rc) * HD + h];
      xs[h] = a;
    }
    __syncthreads();
    const int o = og * 64 + (tid >> 2);
    const int q = tid & 3;
    const f32x4* wr = (const f32x4*)(Wk + (size_t)o * HD);
    const f32x4* x4 = (const f32x4*)xs;
    float a = 0;
#pragma unroll 8
    for (int i = 0; i < 64; ++i) {
      f32x4 w = wr[q * 64 + i], x = x4[q * 64 + i];
      a += w[0] * x[0] + w[1] * x[1] + w[2] * x[2] + w[3] * x[3];
    }
    a += __shfl_xor(a, 1);
    a += __shfl_xor(a, 2);
    if (q == 0) cm[b * HD + o] = a * (1.0f / SD) + bk[o];
  }
}

// ---------------------------------------------------------------------------
// 4) pv_epi: blocks 0..511  -> softmax+PV (32 q-rows x 128 H-cols; K staged
//            from bf16); hc==0 blocks scatter band probs into zeroed P0.
//            blocks 512..1023 -> out[1:4] broadcast of cm
// ---------------------------------------------------------------------------
__global__ __launch_bounds__(256, 2) void pv_epi(
    const float* __restrict__ Sb0, const float* __restrict__ Sb1,
    const ushort_t* __restrict__ Kb, const float* __restrict__ cm,
    float* __restrict__ out0, float* __restrict__ P0,
    float* __restrict__ out123)
{
  __shared__ __align__(16) float smem[15488];   // 61952 B
  const int bid = blockIdx.x;
  const int t = threadIdx.x;

  if (bid < 512) {
    float* Ks  = smem;            // [96][128]
    float* spl = smem + 12288;    // [32][100] padded
    const int i0 = (bid >> 3) * 32;
    const int hc = bid & 7;       // 128 cols each

    // stage K rows [i0-64, i0+31] from bf16, converting to f32
    for (int e = t; e < 96 * 16; e += 256) {
      int lr = e >> 4, c8 = e & 15;
      int gr = i0 - 64 + lr;
      if (gr < 0) gr = 0;
      ushortx8 u = *(const ushortx8*)&Kb[(size_t)gr * HD + hc * 128 + c8 * 8];
      f32x4 f0 = {bf2f(u[0]), bf2f(u[1]), bf2f(u[2]), bf2f(u[3])};
      f32x4 f1 = {bf2f(u[4]), bf2f(u[5]), bf2f(u[6]), bf2f(u[7])};
      *(f32x4*)&Ks[lr * 128 + c8 * 8]     = f0;
      *(f32x4*)&Ks[lr * 128 + c8 * 8 + 4] = f1;
    }

    {
      const int r = t >> 3, sub = t & 7;
      const int i = i0 + r;
      const int jlo = (i >= 64) ? i - 64 : 0;
      const int scoff = i0 & 32;  // Sb col = lj + scoff
      float sv[12];
      float m = -1e30f;
#pragma unroll
      for (int k = 0; k < 12; ++k) {
        int lj = sub + 8 * k;
        int gj = i0 - 64 + lj;
        bool val = (gj >= jlo) && (gj <= i);
        float s = -1e30f;
        if (val) {
          size_t sidx = (size_t)i * 128 + lj + scoff;
          s = Sb0[sidx] + Sb1[sidx];
        }
        sv[k] = s;
        m = fmaxf(m, s);
      }
#pragma unroll
      for (int off = 1; off < 8; off <<= 1) m = fmaxf(m, __shfl_xor(m, off));
      float p[12], sum = 0;
#pragma unroll
      for (int k = 0; k < 12; ++k) {
        p[k] = (sv[k] > -1e29f) ? __expf(sv[k] - m) : 0.0f;
        sum += p[k];
      }
#pragma unroll
      for (int off = 1; off < 8; off <<= 1) sum += __shfl_xor(sum, off);
      float inv = 1.0f / sum;
#pragma unroll
      for (int k = 0; k < 12; ++k) {
        int lj = sub + 8 * k;
        float pv = p[k] * inv;
        spl[r * 100 + lj] = pv;
        if (hc == 0 && sv[k] > -1e29f)
          P0[(size_t)i * SD + (i0 - 64 + lj)] = pv;   // scatter into zeroed row
      }
    }
    __syncthreads();

    const int r = t >> 3;               // 0..31
    const int g = t & 7;                // col sub-group
    f32x4 a0 = {0,0,0,0}, a1 = {0,0,0,0}, a2 = {0,0,0,0}, a3 = {0,0,0,0};
    for (int lj = 0; lj < 96; ++lj) {
      float pv = spl[r * 100 + lj];
      const float* kr = &Ks[lj * 128 + g * 4];
      a0 += pv * *(const f32x4*)(kr);
      a1 += pv * *(const f32x4*)(kr + 32);
      a2 += pv * *(const f32x4*)(kr + 64);
      a3 += pv * *(const f32x4*)(kr + 96);
    }
    float* ob = out0 + (size_t)(i0 + r) * HD + hc * 128 + g * 4;
    *(f32x4*)(ob)      = a0;
    *(f32x4*)(ob + 32) = a1;
    *(f32x4*)(ob + 64) = a2;
    *(f32x4*)(ob + 96) = a3;
    return;
  }

  // out[1:4] broadcast (512 blocks)
  {
    const int nf4 = 3 * SD * (HD / 4);
    const int per_b = SD * (HD / 4);
    const f32x4* cm4 = (const f32x4*)cm;
    f32x4* o4 = (f32x4*)out123;
    for (int idx = (bid - 512) * 256 + t; idx < nf4; idx += 512 * 256) {
      int b = idx / per_b;
      int h4 = idx & (HD / 4 - 1);
      o4[idx] = cm4[b * (HD / 4) + h4];
    }
  }
}

extern "C" void kernel_launch(void* const* d_in, const int* in_sizes, int n_in,
                              void* d_out, int out_size, void* d_ws, size_t ws_size,
                              hipStream_t stream)
{
  (void)in_sizes; (void)n_in; (void)out_size; (void)ws_size;
  const float* X  = (const float*)d_in[0];
  const float* Wk = (const float*)d_in[1];
  const float* bk = (const float*)d_in[2];
  const float* Wq = (const float*)d_in[3];
  const float* bq = (const float*)d_in[4];
  // d_in[5] = k_mul = 64 (band width, hard-coded)

  float* out = (float*)d_out;                   // (B,S,H)
  float* pat = out + (size_t)BD * SD * HD;      // (B,S,S)

  char* w = (char*)d_ws;
  ushort_t* Xb   = (ushort_t*)w; w += (size_t)SD * HD * 2;       // relu(X[0]) bf16
  ushort_t* Wkb  = (ushort_t*)w; w += (size_t)HD * HD * 2;
  ushort_t* Wqb  = (ushort_t*)w; w += (size_t)HD * HD * 2;
  ushort_t* Kb0  = (ushort_t*)w; w += (size_t)SD * HD * 2;       // K[0] bf16
  ushort_t* Q0b  = (ushort_t*)w; w += (size_t)SD * HD * 2;       // Q[0] bf16
  float*    part = (float*)w;    w += (size_t)3 * 32 * HD * 4;   // xsum partials
  float*    cm   = (float*)w;    w += (size_t)3 * HD * 4;        // colmeans b=1..3
  float*    Sb0  = (float*)w;    w += (size_t)SD * 128 * 4;      // band scores, K-half 0
  float*    Sb1  = (float*)w;    w += (size_t)SD * 128 * 4;      // band scores, K-half 1

  prep<<<2048, 256, 0, stream>>>(X, Wk, Wq, Xb, Wkb, Wqb);
  gemm_kq<<<480, 256, 0, stream>>>(Xb, Wkb, Wqb, bk, bq, Kb0, Q0b, X, part, pat);
  band_cm<<<558, 256, 0, stream>>>(Q0b, Kb0, Sb0, Sb1, part, Wk, bk, cm,
                                   pat + (size_t)SD * SD);
  pv_epi<<<1024, 256, 0, stream>>>(Sb0, Sb1, Kb0, cm, out, pat, out + (size_t)SD * HD);
}